// Round 11
// baseline (123.170 us; speedup 1.0000x reference)
//
#include <hip/hip_runtime.h>
#include <math.h>

#define AA    64    // batch
#define SEQ   256   // per-path length
#define LL    511   // number of increments
#define MPAD  320   // real m iterations: 319 (256 pairs + 63 skew); m=319 inert
#define CH    12    // m-iterations per chunk (6 producer waves x 2 each)
#define NCHK  27    // 27*12 = 324 >= 320 (tail m's fully masked/inactive)

typedef float v2f __attribute__((ext_vector_type(2)));
typedef float v4f __attribute__((ext_vector_type(4)));

__global__ void zero_out_kernel(float* out) { out[0] = 0.0f; }

// Full-wave lane shift by 1 (DPP wave_shr:1, ctrl 0x138). Lane 0 <- `fill`.
__device__ __forceinline__ float wave_shr1(float x, float fill) {
    int r = __builtin_amdgcn_update_dpp(__float_as_int(fill), __float_as_int(x),
                                        0x138, 0xF, 0xF, false);
    return __int_as_float(r);
}

// Z point p (0..511) of batch a: X rows then flipped Y rows.
__device__ __forceinline__ const float* zptr(const float* __restrict__ X,
                                             const float* __restrict__ Y,
                                             int a, int p) {
    return (p < SEQ) ? (X + ((size_t)a * SEQ + p) * 8)
                     : (Y + ((size_t)a * SEQ + (LL - p)) * 8);
}
__device__ __forceinline__ void zload(const float* p, v2f z[4]) {
    float4 u = reinterpret_cast<const float4*>(p)[0];
    float4 v = reinterpret_cast<const float4*>(p)[1];
    z[0].x = u.x; z[0].y = u.y; z[1].x = u.z; z[1].y = u.w;
    z[2].x = v.x; z[2].y = v.y; z[3].x = v.z; z[3].y = v.w;
}

// Produce one m-iteration of E into LDS (proven R9 semantics):
// f[k] = <dz[8t+k], dz[2(m-t)]> - 1, f[8+k] = <dz[8t+k], dz[2(m-t)+1]> - 1,
// zeros when (m,t) out of range. Column dz from parity-split LDS (8B lane
// stride, conflict-free).
__device__ __forceinline__ void produce_m_lds(
        int t, int m, const v2f rowdz[8][4], const v2f (*dzs)[2][256],
        float* __restrict__ ebase) {
    const int pm0 = m - t;
    const bool v0 = (unsigned)pm0 < 256u;   // grid col 2pm+1 valid
    const bool v1 = (unsigned)pm0 < 255u;   // grid col 2pm+2 valid
    const int pm = pm0 < 0 ? 0 : (pm0 > 255 ? 255 : pm0);

    v2f c0[4], c1[4];
    #pragma unroll
    for (int p = 0; p < 4; ++p) {
        c0[p] = dzs[p][0][pm];   // dz[2pm]
        c1[p] = dzs[p][1][pm];   // dz[2pm+1] ([1][255] = dz[511] = 0)
    }

    union { v4f q[4]; float f[16]; } eb;
    #pragma unroll
    for (int k = 0; k < 8; ++k) {
        v2f a0 = {-0.5f, -0.5f}, a1 = {-0.5f, -0.5f};
        #pragma unroll
        for (int p = 0; p < 4; ++p) {
            a0 += rowdz[k][p] * c0[p];
            a1 += rowdz[k][p] * c1[p];
        }
        eb.f[k]     = v0 ? (a0.x + a0.y) : 0.0f;
        eb.f[8 + k] = v1 ? (a1.x + a1.y) : 0.0f;
    }
    #pragma unroll
    for (int qi = 0; qi < 4; ++qi)
        *reinterpret_cast<v4f*>(ebase + qi * 256 + t * 4) = eb.q[qi];
}

// Sweep step, exec-branch version of the proven cndmask PROCM. The DPPs are
// hoisted above the divergent branch (and pinned with an asm tie so the
// compiler cannot sink them under partial exec); L/bot updates are predicated
// by exec instead of 16 per-k cndmasks. bot freeze for exec-off lanes is
// consumed only by already-invalid neighbor steps (safe).
#define F0(MI, k) (Rg[MI][(k) >> 2][(k) & 3])
#define F1(MI, k) (Rg[MI][2 + ((k) >> 2)][(k) & 3])
#define PROCM(MI, m_)                                                          \
    { const int pm = (m_) - t;                                                 \
      float sb0 = wave_shr1(bot0, 1.0f);                                       \
      float sb1 = wave_shr1(bot1, 1.0f);                                       \
      asm volatile("" : "+v"(sb0), "+v"(sb1));                                 \
      if ((unsigned)pm < 256u) {                                               \
          float up = sb0, diag = nb_prev;                                      \
          _Pragma("unroll")                                                    \
          for (int k = 0; k < 8; ++k) {                                        \
              const float nv = fmaf(diag, F0(MI, k), L[k]) + up;               \
              diag = L[k]; L[k] = nv; up = nv;                                 \
          }                                                                    \
          bot0 = L[7];                                                         \
          if (pm < 255) {                                                      \
              up = sb1; diag = sb0;                                            \
              _Pragma("unroll")                                                \
              for (int k = 0; k < 8; ++k) {                                    \
                  const float nv = fmaf(diag, F1(MI, k), L[k]) + up;           \
                  diag = L[k]; L[k] = nv; up = nv;                             \
              }                                                                \
              bot1 = L[7];                                                     \
          }                                                                    \
      }                                                                        \
      nb_prev = sb1; }

// One block per batch element. Waves 0..5 produce chunk c+1 (2 m's each)
// into Ebuf[(c+1)&1] while wave 6 (s_setprio(1)) sweeps chunk c from
// Ebuf[c&1]; one __syncthreads per chunk (27 total).
__global__ __launch_bounds__(448) void fused_kernel(
        const float* __restrict__ X, const float* __restrict__ Y,
        float* __restrict__ out) {
    const int a  = blockIdx.x;
    const int wv = threadIdx.x >> 6;   // 0..5 producers, 6 sweeper
    const int t  = threadIdx.x & 63;

    __shared__ __align__(16) float Ebuf[2][CH][1024];    // 96 KB
    __shared__ __align__(16) v2f  dzs[4][2][256];        // 16 KB

    // ---- stage dz into LDS (one pass; dz[511] = 0) ----
    for (int i = threadIdx.x; i < 512; i += 448) {
        v2f d[4];
        if (i < LL) {
            v2f za[4], zb[4];
            zload(zptr(X, Y, a, i),     za);
            zload(zptr(X, Y, a, i + 1), zb);
            #pragma unroll
            for (int p = 0; p < 4; ++p) d[p] = zb[p] - za[p];
        } else {
            #pragma unroll
            for (int p = 0; p < 4; ++p) { d[p].x = 0.0f; d[p].y = 0.0f; }
        }
        #pragma unroll
        for (int p = 0; p < 4; ++p) dzs[p][i & 1][i >> 1] = d[p];
    }
    __syncthreads();

    // ---- producer persistent state + chunk-0 prologue ----
    v2f rowdz[8][4];
    if (wv < 6) {
        #pragma unroll
        for (int k = 0; k < 8; ++k) {
            const int r = 8 * t + k;
            #pragma unroll
            for (int p = 0; p < 4; ++p) rowdz[k][p] = dzs[p][r & 1][r >> 1];
        }
        produce_m_lds(t, wv,     rowdz, dzs, &Ebuf[0][wv][0]);
        produce_m_lds(t, wv + 6, rowdz, dzs, &Ebuf[0][wv + 6][0]);
    }

    // ---- sweeper persistent state ----
    float L[8];
    #pragma unroll
    for (int k = 0; k < 8; ++k) L[k] = 1.0f;
    float bot0 = 1.0f, bot1 = 1.0f, nb_prev = 1.0f;

    if (wv == 6) __builtin_amdgcn_s_setprio(1);   // sweeper wins co-issue
    __syncthreads();

    for (int c = 0; c < NCHK; ++c) {
        if (wv < 6) {
            const int cc = c + 1;
            if (cc < NCHK) {
                const int mb = cc * CH;
                produce_m_lds(t, mb + wv,     rowdz, dzs, &Ebuf[cc & 1][wv][0]);
                produce_m_lds(t, mb + 6 + wv, rowdz, dzs, &Ebuf[cc & 1][wv + 6][0]);
            }
        } else {
            // consume chunk c: 48 ds_read_b128 into regs, then 12 PROC steps
            const float* bp = &Ebuf[c & 1][0][0] + t * 4;
            v4f Rg[CH][4];
            #pragma unroll
            for (int mi = 0; mi < CH; ++mi)
                #pragma unroll
                for (int qi = 0; qi < 4; ++qi)
                    Rg[mi][qi] = *reinterpret_cast<const v4f*>(bp + mi * 1024 + qi * 256);
            const int mb = c * CH;
            PROCM(0,  mb);      PROCM(1,  mb + 1);  PROCM(2,  mb + 2);
            PROCM(3,  mb + 3);  PROCM(4,  mb + 4);  PROCM(5,  mb + 5);
            PROCM(6,  mb + 6);  PROCM(7,  mb + 7);  PROCM(8,  mb + 8);
            PROCM(9,  mb + 9);  PROCM(10, mb + 10); PROCM(11, mb + 11);
        }
        __syncthreads();
    }

    // K[511][511]: sweeper lane 63, grid row 511 = 8*63 + 6 + 1 -> L[6]
    if (wv == 6 && t == 63)
        atomicAdd(out, sqrtf(L[6] - 1.0f) * (1.0f / (float)AA));
}

extern "C" void kernel_launch(void* const* d_in, const int* in_sizes, int n_in,
                              void* d_out, int out_size, void* d_ws, size_t ws_size,
                              hipStream_t stream) {
    const float* X = (const float*)d_in[0];
    const float* Y = (const float*)d_in[1];
    float* out = (float*)d_out;

    zero_out_kernel<<<1, 1, 0, stream>>>(out);
    fused_kernel<<<AA, 448, 0, stream>>>(X, Y, out);
}

// Round 12
// 110.261 us; speedup vs baseline: 1.1171x; 1.1171x over previous
//
#include <hip/hip_runtime.h>
#include <math.h>

#define AA    64    // batch
#define SEQ   256   // per-path length
#define LL    511   // number of increments
#define MPAD  320   // real m iterations: 319 (256 pairs + 63 skew); m=319 inert
#define CH    12    // m-iterations per chunk (6 producer waves x 2 each)
#define NCHK  27    // 27*12 = 324 >= 320 (tail m's fully masked/inactive)

typedef float v2f __attribute__((ext_vector_type(2)));
typedef float v4f __attribute__((ext_vector_type(4)));

__global__ void zero_out_kernel(float* out) { out[0] = 0.0f; }

// Full-wave lane shift by 1 (DPP wave_shr:1, ctrl 0x138). Lane 0 <- `fill`.
__device__ __forceinline__ float wave_shr1(float x, float fill) {
    int r = __builtin_amdgcn_update_dpp(__float_as_int(fill), __float_as_int(x),
                                        0x138, 0xF, 0xF, false);
    return __int_as_float(r);
}

// Z point p (0..511) of batch a: X rows then flipped Y rows.
__device__ __forceinline__ const float* zptr(const float* __restrict__ X,
                                             const float* __restrict__ Y,
                                             int a, int p) {
    return (p < SEQ) ? (X + ((size_t)a * SEQ + p) * 8)
                     : (Y + ((size_t)a * SEQ + (LL - p)) * 8);
}
__device__ __forceinline__ void zload(const float* p, v2f z[4]) {
    float4 u = reinterpret_cast<const float4*>(p)[0];
    float4 v = reinterpret_cast<const float4*>(p)[1];
    z[0].x = u.x; z[0].y = u.y; z[1].x = u.z; z[1].y = u.w;
    z[2].x = v.x; z[2].y = v.y; z[3].x = v.z; z[3].y = v.w;
}

// Produce one m-iteration of E into LDS (proven R9 semantics):
// f[k] = <dz[8t+k], dz[2(m-t)]> - 1, f[8+k] = <dz[8t+k], dz[2(m-t)+1]> - 1,
// zeros when (m,t) out of range. Column dz from parity-split LDS (8B lane
// stride, conflict-free).
__device__ __forceinline__ void produce_m_lds(
        int t, int m, const v2f rowdz[8][4], const v2f (*dzs)[2][256],
        float* __restrict__ ebase) {
    const int pm0 = m - t;
    const bool v0 = (unsigned)pm0 < 256u;   // grid col 2pm+1 valid
    const bool v1 = (unsigned)pm0 < 255u;   // grid col 2pm+2 valid
    const int pm = pm0 < 0 ? 0 : (pm0 > 255 ? 255 : pm0);

    v2f c0[4], c1[4];
    #pragma unroll
    for (int p = 0; p < 4; ++p) {
        c0[p] = dzs[p][0][pm];   // dz[2pm]
        c1[p] = dzs[p][1][pm];   // dz[2pm+1] ([1][255] = dz[511] = 0)
    }

    union { v4f q[4]; float f[16]; } eb;
    #pragma unroll
    for (int k = 0; k < 8; ++k) {
        v2f a0 = {-0.5f, -0.5f}, a1 = {-0.5f, -0.5f};
        #pragma unroll
        for (int p = 0; p < 4; ++p) {
            a0 += rowdz[k][p] * c0[p];
            a1 += rowdz[k][p] * c1[p];
        }
        eb.f[k]     = v0 ? (a0.x + a0.y) : 0.0f;
        eb.f[8 + k] = v1 ? (a1.x + a1.y) : 0.0f;
    }
    #pragma unroll
    for (int qi = 0; qi < 4; ++qi)
        *reinterpret_cast<v4f*>(ebase + qi * 256 + t * 4) = eb.q[qi];
}

// Sweep step, exec-branch version (proven-value math; DPPs hoisted above the
// divergent branch and pinned with an asm tie). bot freeze for exec-off lanes
// is consumed only by already-invalid neighbor steps (safe).
#define F0(MI, k) (Rg[MI][(k) >> 2][(k) & 3])
#define F1(MI, k) (Rg[MI][2 + ((k) >> 2)][(k) & 3])
#define PROCM(MI, m_)                                                          \
    { const int pm = (m_) - t;                                                 \
      float sb0 = wave_shr1(bot0, 1.0f);                                       \
      float sb1 = wave_shr1(bot1, 1.0f);                                       \
      asm volatile("" : "+v"(sb0), "+v"(sb1));                                 \
      if ((unsigned)pm < 256u) {                                               \
          float up = sb0, diag = nb_prev;                                      \
          _Pragma("unroll")                                                    \
          for (int k = 0; k < 8; ++k) {                                        \
              const float nv = fmaf(diag, F0(MI, k), L[k]) + up;               \
              diag = L[k]; L[k] = nv; up = nv;                                 \
          }                                                                    \
          bot0 = L[7];                                                         \
          if (pm < 255) {                                                      \
              up = sb1; diag = sb0;                                            \
              _Pragma("unroll")                                                \
              for (int k = 0; k < 8; ++k) {                                    \
                  const float nv = fmaf(diag, F1(MI, k), L[k]) + up;           \
                  diag = L[k]; L[k] = nv; up = nv;                             \
              }                                                                \
              bot1 = L[7];                                                     \
          }                                                                    \
      }                                                                        \
      nb_prev = sb1; }

// One block per batch element. Waves 0..5 produce chunk c+1 (2 m's each)
// into Ebuf[(c+1)&1] while wave 6 (s_setprio(1)) sweeps chunk c from
// Ebuf[c&1] in two register-halves of 6 m (Rg stays at 96 VGPRs, no spill);
// one __syncthreads per chunk (27 total).
__global__ __launch_bounds__(448) void fused_kernel(
        const float* __restrict__ X, const float* __restrict__ Y,
        float* __restrict__ out) {
    const int a  = blockIdx.x;
    const int wv = threadIdx.x >> 6;   // 0..5 producers, 6 sweeper
    const int t  = threadIdx.x & 63;

    __shared__ __align__(16) float Ebuf[2][CH][1024];    // 96 KB
    __shared__ __align__(16) v2f  dzs[4][2][256];        // 16 KB

    // ---- stage dz into LDS (one pass; dz[511] = 0) ----
    for (int i = threadIdx.x; i < 512; i += 448) {
        v2f d[4];
        if (i < LL) {
            v2f za[4], zb[4];
            zload(zptr(X, Y, a, i),     za);
            zload(zptr(X, Y, a, i + 1), zb);
            #pragma unroll
            for (int p = 0; p < 4; ++p) d[p] = zb[p] - za[p];
        } else {
            #pragma unroll
            for (int p = 0; p < 4; ++p) { d[p].x = 0.0f; d[p].y = 0.0f; }
        }
        #pragma unroll
        for (int p = 0; p < 4; ++p) dzs[p][i & 1][i >> 1] = d[p];
    }
    __syncthreads();

    // ---- producer persistent state + chunk-0 prologue ----
    v2f rowdz[8][4];
    if (wv < 6) {
        #pragma unroll
        for (int k = 0; k < 8; ++k) {
            const int r = 8 * t + k;
            #pragma unroll
            for (int p = 0; p < 4; ++p) rowdz[k][p] = dzs[p][r & 1][r >> 1];
        }
        produce_m_lds(t, wv,     rowdz, dzs, &Ebuf[0][wv][0]);
        produce_m_lds(t, wv + 6, rowdz, dzs, &Ebuf[0][wv + 6][0]);
    }

    // ---- sweeper persistent state ----
    float L[8];
    #pragma unroll
    for (int k = 0; k < 8; ++k) L[k] = 1.0f;
    float bot0 = 1.0f, bot1 = 1.0f, nb_prev = 1.0f;

    if (wv == 6) __builtin_amdgcn_s_setprio(1);   // sweeper wins co-issue
    __syncthreads();

    for (int c = 0; c < NCHK; ++c) {
        if (wv < 6) {
            const int cc = c + 1;
            if (cc < NCHK) {
                const int mb = cc * CH;
                produce_m_lds(t, mb + wv,     rowdz, dzs, &Ebuf[cc & 1][wv][0]);
                produce_m_lds(t, mb + 6 + wv, rowdz, dzs, &Ebuf[cc & 1][wv + 6][0]);
            }
        } else {
            // consume chunk c in two halves of 6 m: Rg stays 24 v4f (96 VGPR)
            const float* bp = &Ebuf[c & 1][0][0] + t * 4;
            const int mb = c * CH;
            v4f Rg[6][4];
            // half 1: m = mb .. mb+5
            #pragma unroll
            for (int mi = 0; mi < 6; ++mi)
                #pragma unroll
                for (int qi = 0; qi < 4; ++qi)
                    Rg[mi][qi] = *reinterpret_cast<const v4f*>(bp + mi * 1024 + qi * 256);
            PROCM(0, mb);     PROCM(1, mb + 1); PROCM(2, mb + 2);
            PROCM(3, mb + 3); PROCM(4, mb + 4); PROCM(5, mb + 5);
            // half 2: m = mb+6 .. mb+11 (data already in LDS; no barrier)
            #pragma unroll
            for (int mi = 0; mi < 6; ++mi)
                #pragma unroll
                for (int qi = 0; qi < 4; ++qi)
                    Rg[mi][qi] = *reinterpret_cast<const v4f*>(bp + (6 + mi) * 1024 + qi * 256);
            PROCM(0, mb + 6);  PROCM(1, mb + 7);  PROCM(2, mb + 8);
            PROCM(3, mb + 9);  PROCM(4, mb + 10); PROCM(5, mb + 11);
        }
        __syncthreads();
    }

    // K[511][511]: sweeper lane 63, grid row 511 = 8*63 + 6 + 1 -> L[6]
    if (wv == 6 && t == 63)
        atomicAdd(out, sqrtf(L[6] - 1.0f) * (1.0f / (float)AA));
}

extern "C" void kernel_launch(void* const* d_in, const int* in_sizes, int n_in,
                              void* d_out, int out_size, void* d_ws, size_t ws_size,
                              hipStream_t stream) {
    const float* X = (const float*)d_in[0];
    const float* Y = (const float*)d_in[1];
    float* out = (float*)d_out;

    zero_out_kernel<<<1, 1, 0, stream>>>(out);
    fused_kernel<<<AA, 448, 0, stream>>>(X, Y, out);
}

// Round 14
// 104.876 us; speedup vs baseline: 1.1744x; 1.0513x over previous
//
#include <hip/hip_runtime.h>
#include <math.h>

#define AA    64    // batch
#define SEQ   256   // per-path length
#define LL    511   // number of increments
#define MPAD  320   // real m iterations: 319 (256 pairs + 63 skew); m=319 inert
#define CH    6     // m-iterations per chunk (one per producer wave) — R9 proven
#define NCHK  54    // 54*6 = 324 >= 320 (tail m's fully masked/inactive)

typedef float v2f __attribute__((ext_vector_type(2)));
typedef float v4f __attribute__((ext_vector_type(4)));

__global__ void zero_out_kernel(float* out) { out[0] = 0.0f; }

// Full-wave lane shift by 1 (DPP wave_shr:1, ctrl 0x138). Lane 0 <- `fill`.
__device__ __forceinline__ float wave_shr1(float x, float fill) {
    int r = __builtin_amdgcn_update_dpp(__float_as_int(fill), __float_as_int(x),
                                        0x138, 0xF, 0xF, false);
    return __int_as_float(r);
}

// Z point p (0..511) of batch a: X rows then flipped Y rows.
__device__ __forceinline__ const float* zptr(const float* __restrict__ X,
                                             const float* __restrict__ Y,
                                             int a, int p) {
    return (p < SEQ) ? (X + ((size_t)a * SEQ + p) * 8)
                     : (Y + ((size_t)a * SEQ + (LL - p)) * 8);
}
__device__ __forceinline__ void zload(const float* p, v2f z[4]) {
    float4 u = reinterpret_cast<const float4*>(p)[0];
    float4 v = reinterpret_cast<const float4*>(p)[1];
    z[0].x = u.x; z[0].y = u.y; z[1].x = u.z; z[1].y = u.w;
    z[2].x = v.x; z[2].y = v.y; z[3].x = v.z; z[3].y = v.w;
}

// Produce one m-iteration of E into LDS (proven R9 semantics, byte-identical):
// f[k] = <dz[8t+k], dz[2(m-t)]> - 1, f[8+k] = <dz[8t+k], dz[2(m-t)+1]> - 1,
// zeros when (m,t) out of range. Column dz from parity-split LDS (8B lane
// stride, conflict-free).
__device__ __forceinline__ void produce_m_lds(
        int t, int m, const v2f rowdz[8][4], const v2f (*dzs)[2][256],
        float* __restrict__ ebase) {
    const int pm0 = m - t;
    const bool v0 = (unsigned)pm0 < 256u;   // grid col 2pm+1 valid
    const bool v1 = (unsigned)pm0 < 255u;   // grid col 2pm+2 valid
    const int pm = pm0 < 0 ? 0 : (pm0 > 255 ? 255 : pm0);

    v2f c0[4], c1[4];
    #pragma unroll
    for (int p = 0; p < 4; ++p) {
        c0[p] = dzs[p][0][pm];   // dz[2pm]
        c1[p] = dzs[p][1][pm];   // dz[2pm+1] ([1][255] = dz[511] = 0)
    }

    union { v4f q[4]; float f[16]; } eb;
    #pragma unroll
    for (int k = 0; k < 8; ++k) {
        v2f a0 = {-0.5f, -0.5f}, a1 = {-0.5f, -0.5f};
        #pragma unroll
        for (int p = 0; p < 4; ++p) {
            a0 += rowdz[k][p] * c0[p];
            a1 += rowdz[k][p] * c1[p];
        }
        eb.f[k]     = v0 ? (a0.x + a0.y) : 0.0f;
        eb.f[8 + k] = v1 ? (a1.x + a1.y) : 0.0f;
    }
    #pragma unroll
    for (int qi = 0; qi < 4; ++qi)
        *reinterpret_cast<v4f*>(ebase + qi * 256 + t * 4) = eb.q[qi];
}

// Proven R9 sweep step: store-masked (L[k] = v ? nv : L[k]). The store mask
// is the correct column-freeze — an up-mask alone self-propagates through the
// add chain (R13 NaN post-mortem).
#define F0(MI, k) (Rg[MI][(k) >> 2][(k) & 3])
#define F1(MI, k) (Rg[MI][2 + ((k) >> 2)][(k) & 3])
#define PROCM(MI, m_)                                                          \
    { const int pm = (m_) - t;                                                 \
      const bool v0 = (unsigned)pm < 256u;                                     \
      const bool v1 = (unsigned)pm < 255u;                                     \
      const float sb0 = wave_shr1(bot0, 1.0f);                                 \
      const float sb1 = wave_shr1(bot1, 1.0f);                                 \
      float up = sb0, diag = nb_prev;                                          \
      _Pragma("unroll")                                                        \
      for (int k = 0; k < 8; ++k) {                                            \
          const float nv = fmaf(diag, F0(MI, k), L[k]) + up;                   \
          diag = L[k]; L[k] = v0 ? nv : L[k]; up = nv;                         \
      }                                                                        \
      bot0 = L[7];                                                             \
      up = sb1; diag = sb0;                                                    \
      _Pragma("unroll")                                                        \
      for (int k = 0; k < 8; ++k) {                                            \
          const float nv = fmaf(diag, F1(MI, k), L[k]) + up;                   \
          diag = L[k]; L[k] = v1 ? nv : L[k]; up = nv;                         \
      }                                                                        \
      bot1 = L[7];                                                             \
      nb_prev = sb1; }

// One block per batch element. Waves 0..5 produce chunk c+1 into
// Ebuf[(c+1)&1] while wave 6 (s_setprio(1)) sweeps chunk c from Ebuf[c&1];
// one __syncthreads per chunk (54 total). R9-proven structure; the ONLY
// change vs R9 is the sweeper setprio (clean T5 A/B).
__global__ __launch_bounds__(448) void fused_kernel(
        const float* __restrict__ X, const float* __restrict__ Y,
        float* __restrict__ out) {
    const int a  = blockIdx.x;
    const int wv = threadIdx.x >> 6;   // 0..5 producers, 6 sweeper
    const int t  = threadIdx.x & 63;

    __shared__ __align__(16) float Ebuf[2][CH][1024];    // 48 KB
    __shared__ __align__(16) v2f  dzs[4][2][256];        // 16 KB

    // ---- stage dz into LDS (one pass; dz[511] = 0) ----
    for (int i = threadIdx.x; i < 512; i += 448) {
        v2f d[4];
        if (i < LL) {
            v2f za[4], zb[4];
            zload(zptr(X, Y, a, i),     za);
            zload(zptr(X, Y, a, i + 1), zb);
            #pragma unroll
            for (int p = 0; p < 4; ++p) d[p] = zb[p] - za[p];
        } else {
            #pragma unroll
            for (int p = 0; p < 4; ++p) { d[p].x = 0.0f; d[p].y = 0.0f; }
        }
        #pragma unroll
        for (int p = 0; p < 4; ++p) dzs[p][i & 1][i >> 1] = d[p];
    }
    __syncthreads();

    // ---- producer persistent state + chunk-0 prologue ----
    v2f rowdz[8][4];
    if (wv < CH) {
        #pragma unroll
        for (int k = 0; k < 8; ++k) {
            const int r = 8 * t + k;
            #pragma unroll
            for (int p = 0; p < 4; ++p) rowdz[k][p] = dzs[p][r & 1][r >> 1];
        }
        produce_m_lds(t, wv, rowdz, dzs, &Ebuf[0][wv][0]);
    }

    // ---- sweeper persistent state ----
    float L[8];
    #pragma unroll
    for (int k = 0; k < 8; ++k) L[k] = 1.0f;
    float bot0 = 1.0f, bot1 = 1.0f, nb_prev = 1.0f;

    if (wv == CH) __builtin_amdgcn_s_setprio(1);   // sweeper wins co-issue
    __syncthreads();

    for (int c = 0; c < NCHK; ++c) {
        if (wv < CH) {
            const int cc = c + 1;
            if (cc < NCHK)
                produce_m_lds(t, cc * CH + wv, rowdz, dzs, &Ebuf[cc & 1][wv][0]);
        } else {
            // consume chunk c: 24 ds_read_b128 into regs, then 6 PROC steps
            const float* bp = &Ebuf[c & 1][0][0] + t * 4;
            v4f Rg[CH][4];
            #pragma unroll
            for (int mi = 0; mi < CH; ++mi)
                #pragma unroll
                for (int qi = 0; qi < 4; ++qi)
                    Rg[mi][qi] = *reinterpret_cast<const v4f*>(bp + mi * 1024 + qi * 256);
            const int mb = c * CH;
            PROCM(0, mb);     PROCM(1, mb + 1); PROCM(2, mb + 2);
            PROCM(3, mb + 3); PROCM(4, mb + 4); PROCM(5, mb + 5);
        }
        __syncthreads();
    }

    // K[511][511]: sweeper lane 63, grid row 511 = 8*63 + 6 + 1 -> L[6]
    if (wv == CH && t == 63)
        atomicAdd(out, sqrtf(L[6] - 1.0f) * (1.0f / (float)AA));
}

extern "C" void kernel_launch(void* const* d_in, const int* in_sizes, int n_in,
                              void* d_out, int out_size, void* d_ws, size_t ws_size,
                              hipStream_t stream) {
    const float* X = (const float*)d_in[0];
    const float* Y = (const float*)d_in[1];
    float* out = (float*)d_out;

    zero_out_kernel<<<1, 1, 0, stream>>>(out);
    fused_kernel<<<AA, 448, 0, stream>>>(X, Y, out);
}

// Round 15
// 103.244 us; speedup vs baseline: 1.1930x; 1.0158x over previous
//
#include <hip/hip_runtime.h>
#include <math.h>

#define AA    64    // batch
#define SEQ   256   // per-path length
#define LL    511   // number of increments
#define CH    6     // m-iterations per chunk (one per producer wave)
#define NCHK  54    // 54*6 = 324 >= 320 real m's (tail fully masked)
#define NBUF  4     // E-ring slots (code assumes power of 2 == 4)

typedef float v2f __attribute__((ext_vector_type(2)));
typedef float v4f __attribute__((ext_vector_type(4)));

__global__ void zero_out_kernel(float* out) { out[0] = 0.0f; }

// Full-wave lane shift by 1 (DPP wave_shr:1, ctrl 0x138). Lane 0 <- `fill`.
__device__ __forceinline__ float wave_shr1(float x, float fill) {
    int r = __builtin_amdgcn_update_dpp(__float_as_int(fill), __float_as_int(x),
                                        0x138, 0xF, 0xF, false);
    return __int_as_float(r);
}

// Z point p (0..511) of batch a: X rows then flipped Y rows.
__device__ __forceinline__ const float* zptr(const float* __restrict__ X,
                                             const float* __restrict__ Y,
                                             int a, int p) {
    return (p < SEQ) ? (X + ((size_t)a * SEQ + p) * 8)
                     : (Y + ((size_t)a * SEQ + (LL - p)) * 8);
}
__device__ __forceinline__ void zload(const float* p, v2f z[4]) {
    float4 u = reinterpret_cast<const float4*>(p)[0];
    float4 v = reinterpret_cast<const float4*>(p)[1];
    z[0].x = u.x; z[0].y = u.y; z[1].x = u.z; z[1].y = u.w;
    z[2].x = v.x; z[2].y = v.y; z[3].x = v.z; z[3].y = v.w;
}

// Produce one m-iteration of E into LDS (proven R9 semantics, byte-identical):
// f[k] = <dz[8t+k], dz[2(m-t)]> - 1, f[8+k] = <dz[8t+k], dz[2(m-t)+1]> - 1,
// zeros when (m,t) out of range. Column dz from parity-split LDS.
__device__ __forceinline__ void produce_m_lds(
        int t, int m, const v2f rowdz[8][4], const v2f (*dzs)[2][256],
        float* __restrict__ ebase) {
    const int pm0 = m - t;
    const bool v0 = (unsigned)pm0 < 256u;   // grid col 2pm+1 valid
    const bool v1 = (unsigned)pm0 < 255u;   // grid col 2pm+2 valid
    const int pm = pm0 < 0 ? 0 : (pm0 > 255 ? 255 : pm0);

    v2f c0[4], c1[4];
    #pragma unroll
    for (int p = 0; p < 4; ++p) {
        c0[p] = dzs[p][0][pm];   // dz[2pm]
        c1[p] = dzs[p][1][pm];   // dz[2pm+1] ([1][255] = dz[511] = 0)
    }

    union { v4f q[4]; float f[16]; } eb;
    #pragma unroll
    for (int k = 0; k < 8; ++k) {
        v2f a0 = {-0.5f, -0.5f}, a1 = {-0.5f, -0.5f};
        #pragma unroll
        for (int p = 0; p < 4; ++p) {
            a0 += rowdz[k][p] * c0[p];
            a1 += rowdz[k][p] * c1[p];
        }
        eb.f[k]     = v0 ? (a0.x + a0.y) : 0.0f;
        eb.f[8 + k] = v1 ? (a1.x + a1.y) : 0.0f;
    }
    #pragma unroll
    for (int qi = 0; qi < 4; ++qi)
        *reinterpret_cast<v4f*>(ebase + qi * 256 + t * 4) = eb.q[qi];
}

// Proven R9 sweep step: store-masked (L[k] = v ? nv : L[k]).
#define F0(MI, k) (Rg[MI][(k) >> 2][(k) & 3])
#define F1(MI, k) (Rg[MI][2 + ((k) >> 2)][(k) & 3])
#define PROCM(MI, m_)                                                          \
    { const int pm = (m_) - t;                                                 \
      const bool v0 = (unsigned)pm < 256u;                                     \
      const bool v1 = (unsigned)pm < 255u;                                     \
      const float sb0 = wave_shr1(bot0, 1.0f);                                 \
      const float sb1 = wave_shr1(bot1, 1.0f);                                 \
      float up = sb0, diag = nb_prev;                                          \
      _Pragma("unroll")                                                        \
      for (int k = 0; k < 8; ++k) {                                            \
          const float nv = fmaf(diag, F0(MI, k), L[k]) + up;                   \
          diag = L[k]; L[k] = v0 ? nv : L[k]; up = nv;                         \
      }                                                                        \
      bot0 = L[7];                                                             \
      up = sb1; diag = sb0;                                                    \
      _Pragma("unroll")                                                        \
      for (int k = 0; k < 8; ++k) {                                            \
          const float nv = fmaf(diag, F1(MI, k), L[k]) + up;                   \
          diag = L[k]; L[k] = v1 ? nv : L[k]; up = nv;                         \
      }                                                                        \
      bot1 = L[7];                                                             \
      nb_prev = sb1; }

// Lock-free producer/consumer: NO per-chunk barriers. 4-slot E ring.
// prod_cnt[slot] (monotone, +6 per chunk round) gates the sweeper;
// cons_cnt (monotone chunk count) gates slot reuse by producers.
// LDS ops are per-wave in-order; the "memory"-clobbered lgkmcnt(0) fences
// pin compiler ordering around each flag update (rule #18 discipline).
__global__ __launch_bounds__(448) void fused_kernel(
        const float* __restrict__ X, const float* __restrict__ Y,
        float* __restrict__ out) {
    const int a  = blockIdx.x;
    const int wv = threadIdx.x >> 6;   // 0..5 producers, 6 sweeper
    const int t  = threadIdx.x & 63;

    __shared__ __align__(16) float Ebuf[NBUF][CH][1024];  // 96 KB
    __shared__ __align__(16) v2f  dzs[4][2][256];         // 16 KB
    __shared__ int prod_cnt[NBUF];
    __shared__ int cons_cnt;

    // ---- stage dz into LDS + zero flags (one barrier, the only one) ----
    for (int i = threadIdx.x; i < 512; i += 448) {
        v2f d[4];
        if (i < LL) {
            v2f za[4], zb[4];
            zload(zptr(X, Y, a, i),     za);
            zload(zptr(X, Y, a, i + 1), zb);
            #pragma unroll
            for (int p = 0; p < 4; ++p) d[p] = zb[p] - za[p];
        } else {
            #pragma unroll
            for (int p = 0; p < 4; ++p) { d[p].x = 0.0f; d[p].y = 0.0f; }
        }
        #pragma unroll
        for (int p = 0; p < 4; ++p) dzs[p][i & 1][i >> 1] = d[p];
    }
    if (threadIdx.x < NBUF) prod_cnt[threadIdx.x] = 0;
    if (threadIdx.x == NBUF) cons_cnt = 0;
    __syncthreads();

    if (wv < CH) {
        // ---------------- producer wave ----------------
        v2f rowdz[8][4];
        #pragma unroll
        for (int k = 0; k < 8; ++k) {
            const int r = 8 * t + k;
            #pragma unroll
            for (int p = 0; p < 4; ++p) rowdz[k][p] = dzs[p][r & 1][r >> 1];
        }
        volatile int* vcons = &cons_cnt;
        for (int c = 0; c < NCHK; ++c) {
            if (c >= NBUF) {   // wait for slot's previous occupant consumed
                while (*vcons < c - (NBUF - 1)) __builtin_amdgcn_s_sleep(2);
            }
            produce_m_lds(t, c * CH + wv, rowdz, dzs, &Ebuf[c & (NBUF - 1)][wv][0]);
            asm volatile("s_waitcnt lgkmcnt(0)" ::: "memory");  // data visible
            if (t == 0) atomicAdd(&prod_cnt[c & (NBUF - 1)], 1);
        }
    } else {
        // ---------------- sweeper wave ----------------
        __builtin_amdgcn_s_setprio(1);   // beat spinning producers to issue
        float L[8];
        #pragma unroll
        for (int k = 0; k < 8; ++k) L[k] = 1.0f;
        float bot0 = 1.0f, bot1 = 1.0f, nb_prev = 1.0f;

        volatile int* vp = prod_cnt;
        for (int c = 0; c < NCHK; ++c) {
            const int slot = c & (NBUF - 1);
            const int need = 6 * ((c >> 2) + 1);   // NBUF == 4
            while (vp[slot] < need) __builtin_amdgcn_s_sleep(1);
            asm volatile("s_waitcnt lgkmcnt(0)" ::: "memory");  // acquire

            const float* bp = &Ebuf[slot][0][0] + t * 4;
            v4f Rg[CH][4];
            #pragma unroll
            for (int mi = 0; mi < CH; ++mi)
                #pragma unroll
                for (int qi = 0; qi < 4; ++qi)
                    Rg[mi][qi] = *reinterpret_cast<const v4f*>(bp + mi * 1024 + qi * 256);
            const int mb = c * CH;
            PROCM(0, mb);     PROCM(1, mb + 1); PROCM(2, mb + 2);
            PROCM(3, mb + 3); PROCM(4, mb + 4); PROCM(5, mb + 5);

            asm volatile("s_waitcnt lgkmcnt(0)" ::: "memory");  // release
            if (t == 0) *((volatile int*)&cons_cnt) = c + 1;
        }

        // K[511][511]: lane 63, grid row 511 = 8*63 + 6 + 1 -> L[6]
        if (t == 63) atomicAdd(out, sqrtf(L[6] - 1.0f) * (1.0f / (float)AA));
    }
}

extern "C" void kernel_launch(void* const* d_in, const int* in_sizes, int n_in,
                              void* d_out, int out_size, void* d_ws, size_t ws_size,
                              hipStream_t stream) {
    const float* X = (const float*)d_in[0];
    const float* Y = (const float*)d_in[1];
    float* out = (float*)d_out;

    zero_out_kernel<<<1, 1, 0, stream>>>(out);
    fused_kernel<<<AA, 448, 0, stream>>>(X, Y, out);
}